// Round 2
// baseline (18577.240 us; speedup 1.0000x reference)
//
#include <hip/hip_runtime.h>

#define NB    40
#define RC    128
#define SC    256
#define BATCH 4
#define TLEN  16384
#define TSKIP 4096
#define TT    32

// ---------------------------------------------------------------------------
// One-time weight transform: [oc][ic](k) -> [ic][oc] so inner-loop weight
// loads are float4 and consecutive-oc coalesced.
//   w0T/w1T/wresT : [NB][128][128]  (ic-major)
//   wskipT        : [NB][128][256]  (ic-major)
// ---------------------------------------------------------------------------
__global__ void wtrans_kernel(const float* __restrict__ w_dil,
                              const float* __restrict__ w_res,
                              const float* __restrict__ w_skip,
                              float* __restrict__ w0T, float* __restrict__ w1T,
                              float* __restrict__ wresT, float* __restrict__ wskipT)
{
    int idx = blockIdx.x * blockDim.x + threadIdx.x;
    const int n_dil  = NB * RC * RC;   // 655360
    const int n_skip = NB * RC * SC;   // 1310720
    if (idx < n_dil) {
        int i  = idx / (RC * RC);
        int r  = idx - i * RC * RC;
        int ic = r / RC;
        int oc = r - ic * RC;
        size_t s = (size_t)(i * RC + oc) * RC + ic;
        w0T[idx]   = w_dil[s * 2 + 0];
        w1T[idx]   = w_dil[s * 2 + 1];
        wresT[idx] = w_res[s];
    }
    if (idx < n_skip) {
        int i  = idx / (RC * SC);
        int r  = idx - i * RC * SC;
        int ic = r / SC;
        int oc = r - ic * SC;
        wskipT[idx] = w_skip[(size_t)(i * SC + oc) * RC + ic];
    }
}

// ---------------------------------------------------------------------------
// One residual block: h = conv(dilated) ; g = tanh(h)*sigmoid(h)
// dst = Wres@g + src ; skip_out = Wskip@g (last TSKIP timesteps)
// Tile: 32 timesteps x full 128 channels. t across lanes, oc across register
// tile. LDS: two input taps (Xs0 reused as G after the conv phase).
// ---------------------------------------------------------------------------
__global__ __launch_bounds__(256, 4) void layer_kernel(
    const float* __restrict__ src, float* __restrict__ dst,
    float* __restrict__ skip_out,
    const float* __restrict__ w0T, const float* __restrict__ w1T,
    const float* __restrict__ wresT, const float* __restrict__ wskipT,
    int dilation)
{
    __shared__ float Xs0[RC][TT];   // tap t-d; becomes G after conv phase
    __shared__ float Xs1[RC][TT];   // tap t (also the residual input)

    const int tid = threadIdx.x;
    const int t   = tid & (TT - 1);   // 0..31 (lanes)
    const int g   = tid >> 5;         // 0..7  (register-tile group)
    const int b   = blockIdx.y;
    const int t0  = blockIdx.x * TT;

    const float* srcb = src + (size_t)b * RC * TLEN;

    // stage input tiles (coalesced 32-float rows)
    #pragma unroll
    for (int it = 0; it < RC / 8; ++it) {
        int c   = g + 8 * it;
        int tg  = t0 + t;
        Xs1[c][t] = srcb[(size_t)c * TLEN + tg];
        int tg0 = tg - dilation;
        Xs0[c][t] = (tg0 >= 0) ? srcb[(size_t)c * TLEN + tg0] : 0.0f;
    }
    __syncthreads();

    // ---- dilated conv: H[oc][t], oc = g*16 .. g*16+15 ----
    const int ocb = g * 16;
    float acc[16];
    #pragma unroll
    for (int j = 0; j < 16; ++j) acc[j] = 0.0f;

    #pragma unroll 2
    for (int k = 0; k < RC; ++k) {
        float x0 = Xs0[k][t];
        float x1 = Xs1[k][t];
        const float4* w0p = (const float4*)(w0T + (k * RC + ocb));
        const float4* w1p = (const float4*)(w1T + (k * RC + ocb));
        #pragma unroll
        for (int j4 = 0; j4 < 4; ++j4) {
            float4 w0 = w0p[j4];
            float4 w1 = w1p[j4];
            acc[4*j4+0] += w0.x * x0 + w1.x * x1;
            acc[4*j4+1] += w0.y * x0 + w1.y * x1;
            acc[4*j4+2] += w0.z * x0 + w1.z * x1;
            acc[4*j4+3] += w0.w * x0 + w1.w * x1;
        }
    }
    __syncthreads();   // all reads of Xs0 done before overwrite

    // gated = tanh(h) * sigmoid(h) -> G (in Xs0's storage)
    #pragma unroll
    for (int j = 0; j < 16; ++j) {
        float h  = acc[j];
        float gv = tanhf(h) * (1.0f / (1.0f + __expf(-h)));
        Xs0[ocb + j][t] = gv;
    }
    __syncthreads();

    // ---- residual 1x1: dst = Wres@G + X1 ----
    float racc[16];
    #pragma unroll
    for (int j = 0; j < 16; ++j) racc[j] = 0.0f;

    #pragma unroll 2
    for (int k = 0; k < RC; ++k) {
        float gv = Xs0[k][t];
        const float4* wrp = (const float4*)(wresT + (k * RC + ocb));
        #pragma unroll
        for (int j4 = 0; j4 < 4; ++j4) {
            float4 wr = wrp[j4];
            racc[4*j4+0] += wr.x * gv;
            racc[4*j4+1] += wr.y * gv;
            racc[4*j4+2] += wr.z * gv;
            racc[4*j4+3] += wr.w * gv;
        }
    }
    float* dstb = dst + (size_t)b * RC * TLEN;
    #pragma unroll
    for (int j = 0; j < 16; ++j) {
        dstb[(size_t)(ocb + j) * TLEN + t0 + t] = racc[j] + Xs1[ocb + j][t];
    }

    // ---- skip 1x1 (only last TSKIP timesteps) ----
    if (t0 >= TLEN - TSKIP) {
        const int scb = g * 32;
        float sacc[32];
        #pragma unroll
        for (int j = 0; j < 32; ++j) sacc[j] = 0.0f;

        #pragma unroll 2
        for (int k = 0; k < RC; ++k) {
            float gv = Xs0[k][t];
            const float4* wsp = (const float4*)(wskipT + (k * SC + scb));
            #pragma unroll
            for (int j4 = 0; j4 < 8; ++j4) {
                float4 ws = wsp[j4];
                sacc[4*j4+0] += ws.x * gv;
                sacc[4*j4+1] += ws.y * gv;
                sacc[4*j4+2] += ws.z * gv;
                sacc[4*j4+3] += ws.w * gv;
            }
        }
        // FIX (R1): batch offset was missing -> all batches raced into b=0.
        float* skipb = skip_out + (size_t)b * SC * TSKIP;
        int ts = t0 - (TLEN - TSKIP) + t;
        #pragma unroll
        for (int j = 0; j < 32; ++j) {
            skipb[(size_t)(scb + j) * TSKIP + ts] = sacc[j];
        }
    }
}

// ---------------------------------------------------------------------------
extern "C" void kernel_launch(void* const* d_in, const int* in_sizes, int n_in,
                              void* d_out, int out_size, void* d_ws, size_t ws_size,
                              hipStream_t stream)
{
    const float* x      = (const float*)d_in[0];
    const float* w_dil  = (const float*)d_in[1];
    const float* w_res  = (const float*)d_in[2];
    const float* w_skip = (const float*)d_in[3];
    float* out = (float*)d_out;

    // workspace layout (floats): bufA | bufB | w0T | w1T | wresT | wskipT
    // total = 2*8388608 + 3*655360 + 1310720 = 20,054,016 floats (~80.2 MB)
    float* bufA   = (float*)d_ws;
    float* bufB   = bufA  + (size_t)BATCH * RC * TLEN;
    float* w0T    = bufB  + (size_t)BATCH * RC * TLEN;
    float* w1T    = w0T   + (size_t)NB * RC * RC;
    float* wresT  = w1T   + (size_t)NB * RC * RC;
    float* wskipT = wresT + (size_t)NB * RC * RC;

    wtrans_kernel<<<(NB * RC * SC + 255) / 256, 256, 0, stream>>>(
        w_dil, w_res, w_skip, w0T, w1T, wresT, wskipT);

    for (int i = 0; i < NB; ++i) {
        int d = 1 << (i % 10);
        const float* src = (i == 0) ? x : ((i & 1) ? bufA : bufB);
        float*       dst = (i & 1) ? bufB : bufA;
        float* skip = out + (size_t)i * BATCH * SC * TSKIP;
        dim3 grid(TLEN / TT, BATCH);
        layer_kernel<<<grid, 256, 0, stream>>>(
            src, dst, skip,
            w0T + (size_t)i * RC * RC, w1T + (size_t)i * RC * RC,
            wresT + (size_t)i * RC * RC, wskipT + (size_t)i * RC * SC, d);
    }
}